// Round 15
// baseline (427.206 us; speedup 1.0000x reference)
//
#include <hip/hip_runtime.h>
#include <hip/hip_bf16.h>

#define NN 50000
#define NE 800000
#define DD 128
#define KSEL 25000
#define NBK 391                 // buckets of 128 nodes
#define BC  391                 // build blocks (2048 edges each, 256 thr)
#define AB 12500                // agg node-blocks (4 nodes/block)
#define GB 782                  // gemm blocks (64 rows)
#define GBL 391                 // compacted gemm blocks
#define HB 64                   // hist blocks

typedef unsigned int uint32;
typedef unsigned short ushort16;
typedef __attribute__((ext_vector_type(8))) short bf16x8;
typedef __attribute__((ext_vector_type(4))) float f32x4;

__device__ __forceinline__ float sigmoidf(float x){ return 1.f/(1.f+__expf(-x)); }

__device__ __forceinline__ unsigned short f2b(float f){
  union{float f; unsigned u;} v; v.f=f;
  unsigned r=(v.u + 0x7fffu + ((v.u>>16)&1u))>>16;
  return (unsigned short)r;
}

__device__ __forceinline__ void addbf2(float&lo,float&hi,uint32 u,float w){
  lo+=__uint_as_float(u<<16)*w;
  hi+=__uint_as_float(u&0xffff0000u)*w;
}

__device__ __forceinline__ int aload(const int* p){
  return __hip_atomic_load(p,__ATOMIC_RELAXED,__HIP_MEMORY_SCOPE_AGENT);
}

// ---------- fp32 GEMM body: 64x128 tile, 8 rows x 4 cols per thread ----------
template<int IN_SIG,int ACT>
__device__ __forceinline__ void gemm64_body(float (*Al)[132], int tid, int row0,
    const float* __restrict__ A, const float* __restrict__ W,
    const float* __restrict__ bias, float* __restrict__ outf,
    const float* __restrict__ aparam){
  {
    const float4* A4=(const float4*)(A+(size_t)row0*DD);
    #pragma unroll
    for(int i=0;i<8;i++){
      int idx=i*256+tid;
      int r=idx>>5, c=(idx&31)*4;
      float4 v=make_float4(0.f,0.f,0.f,0.f);
      if(row0+r<NN) v=A4[idx];
      if(IN_SIG){ v.x=sigmoidf(v.x); v.y=sigmoidf(v.y); v.z=sigmoidf(v.z); v.w=sigmoidf(v.w); }
      *(float4*)&Al[r][c]=v;
    }
  }
  __syncthreads();
  int tx=tid&31, ty=tid>>5;
  float acc[8][4];
  #pragma unroll
  for(int i=0;i<8;i++)
    #pragma unroll
    for(int c=0;c<4;c++) acc[i][c]=0.f;
  for(int k=0;k<DD;k+=4){
    float4 wv0=*(const float4*)&W[(size_t)(k+0)*DD+tx*4];
    float4 wv1=*(const float4*)&W[(size_t)(k+1)*DD+tx*4];
    float4 wv2=*(const float4*)&W[(size_t)(k+2)*DD+tx*4];
    float4 wv3=*(const float4*)&W[(size_t)(k+3)*DD+tx*4];
    #pragma unroll
    for(int i=0;i<8;i++){
      float4 a=*(const float4*)&Al[ty+8*i][k];
      acc[i][0]+=a.x*wv0.x+a.y*wv1.x+a.z*wv2.x+a.w*wv3.x;
      acc[i][1]+=a.x*wv0.y+a.y*wv1.y+a.z*wv2.y+a.w*wv3.y;
      acc[i][2]+=a.x*wv0.z+a.y*wv1.z+a.z*wv2.z+a.w*wv3.z;
      acc[i][3]+=a.x*wv0.w+a.y*wv1.w+a.z*wv2.w+a.w*wv3.w;
    }
  }
  float4 bv=make_float4(0.f,0.f,0.f,0.f);
  if(bias) bv=*(const float4*)&bias[tx*4];
  float ap=ACT?aparam[0]:0.f;
  #pragma unroll
  for(int i=0;i<8;i++){
    int r=row0+ty+8*i;
    if(r<NN){
      float4 o;
      o.x=acc[i][0]+bv.x; o.y=acc[i][1]+bv.y; o.z=acc[i][2]+bv.z; o.w=acc[i][3]+bv.w;
      if(ACT){
        o.x=o.x>=0.f?o.x:ap*o.x; o.y=o.y>=0.f?o.y:ap*o.y;
        o.z=o.z>=0.f?o.z:ap*o.z; o.w=o.w>=0.f?o.w:ap*o.w;
      }
      *(float4*)&outf[(size_t)r*DD+tx*4]=o;
    }
  }
}

// ---------- bf16 MFMA body ----------
template<int ROWLIST>
__device__ __forceinline__ void mfma_body(unsigned short (*Asl)[136],
    unsigned short (*Wsl)[136], int tid, int row0,
    const float* __restrict__ A, const ushort16* __restrict__ Wtb,
    ushort16* __restrict__ outb, const int* __restrict__ rlist){
  {
    const uint4* Wg=(const uint4*)Wtb;
    #pragma unroll
    for(int i=0;i<8;i++){
      int idx=i*256+tid;
      int n=idx>>4, k8=(idx&15)*8;
      uint4 v=Wg[idx];
      *(uint4*)&Wsl[n][k8]=v;
    }
  }
  {
    #pragma unroll
    for(int i=0;i<8;i++){
      int idx=i*256+tid;
      int r=idx>>5, c=(idx&31)*4;
      int gr; bool ok;
      if(ROWLIST){ int ri=row0+r; ok=(ri<KSEL); gr=ok?rlist[ri]:0; }
      else { gr=row0+r; ok=(gr<NN); }
      float4 v=make_float4(0.f,0.f,0.f,0.f);
      if(ok) v=*(const float4*)&A[(size_t)gr*DD+c];
      ushort4 pk;
      pk.x=f2b(v.x); pk.y=f2b(v.y); pk.z=f2b(v.z); pk.w=f2b(v.w);
      *(ushort4*)&Asl[r][c]=pk;
    }
  }
  __syncthreads();
  int lane=tid&63, w=tid>>6;
  int lr=lane&15, lk=lane>>4;
  f32x4 acc[8];
  #pragma unroll
  for(int nf=0;nf<8;nf++){ acc[nf][0]=0.f; acc[nf][1]=0.f; acc[nf][2]=0.f; acc[nf][3]=0.f; }
  #pragma unroll
  for(int kk=0;kk<4;kk++){
    int k0=kk*32+lk*8;
    bf16x8 a=*(bf16x8*)&Asl[w*16+lr][k0];
    #pragma unroll
    for(int nf=0;nf<8;nf++){
      bf16x8 b=*(bf16x8*)&Wsl[nf*16+lr][k0];
      acc[nf]=__builtin_amdgcn_mfma_f32_16x16x32_bf16(a,b,acc[nf],0,0,0);
    }
  }
  int orow[4]; bool ok[4];
  #pragma unroll
  for(int i=0;i<4;i++){
    int ri=row0+w*16+lk*4+i;
    if(ROWLIST){ ok[i]=(ri<KSEL); orow[i]=ok[i]?rlist[ri]:0; }
    else { orow[i]=ri; ok[i]=(ri<NN); }
  }
  #pragma unroll
  for(int nf=0;nf<8;nf++){
    int col=nf*16+lr;
    #pragma unroll
    for(int i=0;i<4;i++){
      if(ok[i]) outb[(size_t)orow[i]*DD+col]=f2b(acc[nf][i]);
    }
  }
}

// ====== K1: GEMM1 (feat@Wd,prelu) | bcount | prep ======
__global__ __launch_bounds__(256) void k_pack1(
    const float* __restrict__ feat, const float* __restrict__ Wd,
    const float* __restrict__ bd, float* __restrict__ h_pos,
    const float* __restrict__ aparam,
    const int* __restrict__ dst, int* __restrict__ blkcnt,
    const float* __restrict__ Wbil, float* __restrict__ WbT,
    const float* __restrict__ Wg2, ushort16* __restrict__ Wt2b,
    const float* __restrict__ Wg3, ushort16* __restrict__ Wt3b,
    int* __restrict__ zspan){
  __shared__ float Al[64][132];
  int bid=blockIdx.x, tid=threadIdx.x;
  if(bid<GB){
    gemm64_body<0,1>(Al, tid, bid*64, feat, Wd, bd, h_pos, aparam);
    return;
  }
  if(bid<GB+BC){
    int b=bid-GB;
    int* h=(int*)Al;
    for(int i=tid;i<NBK;i+=256) h[i]=0;
    __syncthreads();
    int e0=b*2048;
    #pragma unroll
    for(int t=0;t<8;t++){
      int e=e0+t*256+tid;
      if(e<NE) atomicAdd(&h[dst[e]>>7],1);
    }
    __syncthreads();
    for(int i=tid;i<NBK;i+=256) blkcnt[b*NBK+i]=h[i];
    return;
  }
  // prep
  int i=(bid-GB-BC)*256+tid;             // 0..16383
  if(i<DD*DD){
    int n=i>>7, k=i&127;
    WbT[i]=Wbil[k*DD+n];
    Wt2b[i]=f2b(Wg2[(size_t)k*DD+n]);
    Wt3b[i]=f2b(Wg3[(size_t)k*DD+n]);
  }
  if(i<8512) zspan[i]=0;                 // ctrl(64) + hist0(4096) + hist1(4096) + hist2(256)
}

// ====== K2: GEMM2 (h_pos@Wg1) | bscan ======
__global__ __launch_bounds__(256) void k_pack2(
    const float* __restrict__ h_pos, const float* __restrict__ Wg1,
    float* __restrict__ xw,
    const int* __restrict__ blkcnt, int* __restrict__ boff,
    int* __restrict__ blkbase, int* __restrict__ row_start){
  __shared__ float Al[64][132];
  int bid=blockIdx.x, tid=threadIdx.x;
  if(bid<GB){
    gemm64_body<0,0>(Al, tid, bid*64, h_pos, Wg1, nullptr, xw, nullptr);
    return;
  }
  // bscan: 256 threads, buckets tid and tid+256
  int* sd=(int*)Al;                      // 512 ints
  int b0=tid, b1=tid+256;
  int s0=0, s1=0;
  for(int b=0;b<BC;b++){
    s0+=blkcnt[b*NBK+b0];
    if(b1<NBK) s1+=blkcnt[b*NBK+b1];
  }
  sd[b0]=s0; sd[b1]=(b1<NBK)?s1:0;
  __syncthreads();
  for(int off=1;off<512;off<<=1){
    int a0=(b0>=off)?sd[b0-off]:0;
    int a1=(b1>=off)?sd[b1-off]:0;
    __syncthreads();
    sd[b0]+=a0; sd[b1]+=a1;
    __syncthreads();
  }
  int excl0=sd[b0]-s0;
  boff[b0]=excl0;
  int excl1=0;
  if(b1<NBK){ excl1=sd[b1]-s1; boff[b1]=excl1; }
  if(tid==0){ boff[NBK]=NE; row_start[NN]=NE; }
  {
    int run=excl0;
    for(int b=0;b<BC;b++){
      int c=blkcnt[b*NBK+b0];
      blkbase[b*NBK+b0]=run;
      run+=c;
    }
  }
  if(b1<NBK){
    int run=excl1;
    for(int b=0;b<BC;b++){
      int c=blkcnt[b*NBK+b1];
      blkbase[b*NBK+b1]=run;
      run+=c;
    }
  }
}

// ---------------- bscatter (256 thr, 2048 edges/block) ----------------
__global__ __launch_bounds__(256) void k_bscatter(const int* __restrict__ src,
    const int* __restrict__ dst, const int* __restrict__ blkbase, uint32* __restrict__ pairs){
  __shared__ int cur[NBK];
  int tid=threadIdx.x, b=blockIdx.x;
  for(int i=tid;i<NBK;i+=256) cur[i]=blkbase[b*NBK+i];
  __syncthreads();
  int e0=b*2048;
  #pragma unroll
  for(int t=0;t<8;t++){
    int e=e0+t*256+tid;
    if(e<NE){
      int d=dst[e];
      int p=atomicAdd(&cur[d>>7],1);
      pairs[p]=(unsigned)src[e] | ((unsigned)(d&127)<<17);
    }
  }
}

__global__ __launch_bounds__(256) void k_bfinal(const uint32* __restrict__ pairs,
    const int* __restrict__ boff, int* __restrict__ row_start,
    float* __restrict__ inv_sq, int* __restrict__ csr_src){
  __shared__ int degl[128];
  __shared__ int cur[128];
  __shared__ int ssum[2];
  int b=blockIdx.x, tid=threadIdx.x;
  int lo=boff[b], hi=boff[b+1];
  if(tid<128) degl[tid]=0;
  __syncthreads();
  for(int e=lo+tid;e<hi;e+=256) atomicAdd(&degl[pairs[e]>>17],1);
  __syncthreads();
  int v=0,x=0;
  if(tid<128){
    v=degl[tid]; x=v;
    #pragma unroll
    for(int off=1;off<64;off<<=1){
      int y=__shfl_up(x,off,64);
      if((tid&63)>=off) x+=y;
    }
    if((tid&63)==63) ssum[tid>>6]=x;
  }
  __syncthreads();
  if(tid<128){
    int incl=x+((tid>=64)?ssum[0]:0);
    int node=b*128+tid;
    int excl=lo+incl-v;
    if(node<NN){
      row_start[node]=excl;
      cur[tid]=excl;
      inv_sq[node]=1.f/sqrtf((float)(v+1));
    }
  }
  __syncthreads();
  for(int e=lo+tid;e<hi;e+=256){
    uint32 u=pairs[e];
    int p=atomicAdd(&cur[u>>17],1);
    csr_src[p]=(int)(u&0x1FFFFu);
  }
}

// ---------------- score GEMM: sigmoid(embed)@WbT, fused bilinear score ------
__global__ __launch_bounds__(256) void k_gemm_score(const float* __restrict__ A,
    const float* __restrict__ W, const float* __restrict__ hp,
    const float* __restrict__ bbil, float* __restrict__ score){
  __shared__ float Al[64][132];
  int tid=threadIdx.x;
  int row0=blockIdx.x*64;
  {
    const float4* A4=(const float4*)(A+(size_t)row0*DD);
    #pragma unroll
    for(int i=0;i<8;i++){
      int idx=i*256+tid;
      int r=idx>>5, c=(idx&31)*4;
      float4 v=make_float4(0.f,0.f,0.f,0.f);
      if(row0+r<NN) v=A4[idx];
      v.x=sigmoidf(v.x); v.y=sigmoidf(v.y); v.z=sigmoidf(v.z); v.w=sigmoidf(v.w);
      *(float4*)&Al[r][c]=v;
    }
  }
  __syncthreads();
  int tx=tid&31, ty=tid>>5;
  float acc[8][4];
  #pragma unroll
  for(int i=0;i<8;i++)
    #pragma unroll
    for(int c=0;c<4;c++) acc[i][c]=0.f;
  for(int k=0;k<DD;k+=4){
    float4 wv0=*(const float4*)&W[(size_t)(k+0)*DD+tx*4];
    float4 wv1=*(const float4*)&W[(size_t)(k+1)*DD+tx*4];
    float4 wv2=*(const float4*)&W[(size_t)(k+2)*DD+tx*4];
    float4 wv3=*(const float4*)&W[(size_t)(k+3)*DD+tx*4];
    #pragma unroll
    for(int i=0;i<8;i++){
      float4 a=*(const float4*)&Al[ty+8*i][k];
      acc[i][0]+=a.x*wv0.x+a.y*wv1.x+a.z*wv2.x+a.w*wv3.x;
      acc[i][1]+=a.x*wv0.y+a.y*wv1.y+a.z*wv2.y+a.w*wv3.y;
      acc[i][2]+=a.x*wv0.z+a.y*wv1.z+a.z*wv2.z+a.w*wv3.z;
      acc[i][3]+=a.x*wv0.w+a.y*wv1.w+a.z*wv2.w+a.w*wv3.w;
    }
  }
  float bb=bbil[0];
  #pragma unroll
  for(int i=0;i<8;i++){
    int r=row0+ty+8*i;
    float p=0.f;
    if(r<NN){
      float4 h=*(const float4*)&hp[(size_t)r*DD+tx*4];
      p=acc[i][0]*h.x+acc[i][1]*h.y+acc[i][2]*h.z+acc[i][3]*h.w;
    }
    p+=__shfl_xor(p,16,64); p+=__shfl_xor(p,8,64);
    p+=__shfl_xor(p,4,64);  p+=__shfl_xor(p,2,64); p+=__shfl_xor(p,1,64);
    if(tx==0 && r<NN) score[r]=sigmoidf(p+bb);
  }
}

// ====== K7: mfma0 (embed@Wg2 -> xwb) | hist0 (findb fused in last block) ======
__global__ __launch_bounds__(256) void k_pack3(const float* __restrict__ embed,
    const ushort16* __restrict__ Wt2b, ushort16* __restrict__ outb,
    const float* __restrict__ score, int* __restrict__ ghist, int* __restrict__ ctrl){
  __shared__ __align__(16) unsigned short Asl[64][136];
  __shared__ __align__(16) unsigned short Wsl[128][136];
  __shared__ int lastf;
  int bid=blockIdx.x, tid=threadIdx.x;
  if(bid<GB){
    mfma_body<0>(Asl, Wsl, tid, bid*64, embed, Wt2b, outb, nullptr);
    return;
  }
  int hb=bid-GB;                         // 0..HB-1
  int* lh=(int*)Asl;                     // 4096 ints = 16 KB
  int* gs=(int*)Wsl;
  for(int i=tid;i<4096;i+=256) lh[i]=0;
  __syncthreads();
  for(int i=hb*256+tid;i<NN;i+=HB*256)
    atomicAdd(&lh[__float_as_uint(score[i])>>20],1);
  __syncthreads();
  for(int i=tid;i<4096;i+=256){ int v=lh[i]; if(v) atomicAdd(&ghist[i],v); }
  __syncthreads();
  if(tid==0){
    __threadfence();
    int v=atomicAdd(&ctrl[8],1);
    lastf=(v==HB-1);
  }
  __syncthreads();
  if(!lastf) return;
  int s=0;
  #pragma unroll
  for(int q=0;q<16;q++) s+=aload(&ghist[tid*16+q]);
  int x=s; gs[tid]=x; __syncthreads();
  for(int off=1;off<256;off<<=1){
    int y=(tid+off<256)?gs[tid+off]:0;
    __syncthreads(); x+=y; gs[tid]=x; __syncthreads();
  }
  int above=x-s, incl=x;
  if(above<KSEL && incl>=KSEL){
    int c=above, B=0;
    for(int b=15;b>=0;b--){
      int hb2=aload(&ghist[tid*16+b]);
      if(c+hb2>=KSEL){ B=tid*16+b; break; }
      c+=hb2;
    }
    ctrl[0]=B; ctrl[1]=c;
  }
}

// ====== hist passes 1,2 (findb fused into last block) ======
template<int NB,int PASS>
__global__ __launch_bounds__(256) void k_hist(const float* __restrict__ score,
    int* __restrict__ ghist, int* __restrict__ ctrl){
  __shared__ int lh[NB];
  __shared__ int gs[256];
  __shared__ int lastf;
  int tid=threadIdx.x;
  for(int i=tid;i<NB;i+=256) lh[i]=0;
  __syncthreads();
  int p0=0,p01=0;
  if(PASS==1) p0=ctrl[0];
  if(PASS==2) p01=ctrl[2];
  for(int i=blockIdx.x*256+tid; i<NN; i+=gridDim.x*256){
    unsigned b=__float_as_uint(score[i]);
    if(PASS==1){ if((int)(b>>20)==p0) atomicAdd(&lh[(b>>8)&0xFFF],1); }
    else { if((int)(b>>8)==p01) atomicAdd(&lh[b&0xFF],1); }
  }
  __syncthreads();
  for(int i=tid;i<NB;i+=256){ int v=lh[i]; if(v) atomicAdd(&ghist[i],v); }
  __syncthreads();
  if(tid==0){
    __threadfence();
    int v=atomicAdd(&ctrl[8+PASS],1);
    lastf=(v==(int)gridDim.x-1);
  }
  __syncthreads();
  if(!lastf) return;
  const int BPT=NB/256;
  int s=0;
  #pragma unroll
  for(int q=0;q<BPT;q++) s+=aload(&ghist[tid*BPT+q]);
  int x=s; gs[tid]=x; __syncthreads();
  for(int off=1;off<256;off<<=1){
    int y=(tid+off<256)?gs[tid+off]:0;
    __syncthreads(); x+=y; gs[tid]=x; __syncthreads();
  }
  int base=(PASS==1)?ctrl[1]:ctrl[3];
  int above=base+x-s, incl=base+x;
  if(above<KSEL && incl>=KSEL){
    int c=above, B=0;
    for(int b=BPT-1;b>=0;b--){
      int hb=aload(&ghist[tid*BPT+b]);
      if(c+hb>=KSEL){ B=tid*BPT+b; break; }
      c+=hb;
    }
    if(PASS==1){ ctrl[2]=(ctrl[0]<<12)|B; ctrl[3]=c; }
    else { ctrl[4]=(int)((((unsigned)ctrl[2])<<8)|(unsigned)B); ctrl[5]=KSEL-c; }
  }
}

// mark + compacted list; tie resolution fused into LAST block
__global__ __launch_bounds__(256) void k_sel(const float* __restrict__ score,
    int* __restrict__ ctrl, int* __restrict__ tie_list,
    unsigned char* __restrict__ sel, int* __restrict__ list){
  __shared__ int lastf;
  int tid=threadIdx.x;
  int i=blockIdx.x*256+tid;
  if(i<NN){
    unsigned b=__float_as_uint(score[i]);
    unsigned thr=(unsigned)ctrl[4];
    if(b>thr){
      sel[i]=1;
      int p=atomicAdd(&ctrl[7],1);
      list[p]=i;
    } else if(b==thr){
      sel[i]=0;
      int p=atomicAdd(&ctrl[6],1);
      if(p<4096) __hip_atomic_store(&tie_list[p],i,__ATOMIC_RELAXED,__HIP_MEMORY_SCOPE_AGENT);
    } else sel[i]=0;
  }
  __syncthreads();
  if(tid==0){
    __threadfence();
    int v=atomicAdd(&ctrl[11],1);
    lastf=(v==(int)gridDim.x-1);
  }
  __syncthreads();
  if(!lastf) return;
  int m=aload(&ctrl[6]); if(m>4096) m=4096;
  int needed=ctrl[5];
  for(int t=tid;t<m;t+=256){
    int idx=aload(&tie_list[t]);
    int rank=0;
    for(int j2=0;j2<m;j2++) rank+=(aload(&tie_list[j2])<idx)?1:0;
    if(rank<needed){
      sel[idx]=1;
      int p=atomicAdd(&ctrl[7],1);
      list[p]=idx;
    }
  }
}

// ============ standalone MFMA GEMM (ROWLIST) ============
__global__ __launch_bounds__(256) void k_gemm_mfma1(const float* __restrict__ A,
    const ushort16* __restrict__ Wtb, ushort16* __restrict__ outb,
    const int* __restrict__ rlist){
  __shared__ __align__(16) unsigned short Asl[64][136];
  __shared__ __align__(16) unsigned short Wsl[128][136];
  mfma_body<1>(Asl, Wsl, threadIdx.x, blockIdx.x*64, A, Wtb, outb, rlist);
}

// ---------------- fp32 GCN aggregation: 8-edge unroll ----------
__global__ __launch_bounds__(256) void k_agg_f32(const float* __restrict__ xw,
    const int* __restrict__ row_start, const int* __restrict__ csr,
    const float* __restrict__ inv, const float* __restrict__ bias,
    float* __restrict__ outp){
  int node=blockIdx.x*4+(threadIdx.x>>6);
  if(node>=NN) return;
  int lane=threadIdx.x&63;
  int g=lane>>5, li=lane&31;
  int rs=row_start[node], re=row_start[node+1];
  float a0=0.f,a1=0.f,a2=0.f,a3=0.f;
  int j=rs;
  for(; j+7<re; j+=8){
    int s0=csr[j+g], s1=csr[j+2+g], s2=csr[j+4+g], s3=csr[j+6+g];
    float w0=inv[s0], w1=inv[s1], w2=inv[s2], w3=inv[s3];
    float4 v0=*(const float4*)&xw[(size_t)s0*DD+li*4];
    float4 v1=*(const float4*)&xw[(size_t)s1*DD+li*4];
    float4 v2=*(const float4*)&xw[(size_t)s2*DD+li*4];
    float4 v3=*(const float4*)&xw[(size_t)s3*DD+li*4];
    a0+=v0.x*w0+v1.x*w1+v2.x*w2+v3.x*w3;
    a1+=v0.y*w0+v1.y*w1+v2.y*w2+v3.y*w3;
    a2+=v0.z*w0+v1.z*w1+v2.z*w2+v3.z*w3;
    a3+=v0.w*w0+v1.w*w1+v2.w*w2+v3.w*w3;
  }
  for(; j+1<re; j+=2){
    int s=csr[j+g];
    float w=inv[s];
    float4 v=*(const float4*)&xw[(size_t)s*DD+li*4];
    a0+=v.x*w; a1+=v.y*w; a2+=v.z*w; a3+=v.w*w;
  }
  if(j<re && g==0){
    int s=csr[j]; float w=inv[s];
    float4 v=*(const float4*)&xw[(size_t)s*DD+li*4];
    a0+=v.x*w; a1+=v.y*w; a2+=v.z*w; a3+=v.w*w;
  }
  if(g==0){
    float wd=inv[node];
    float4 v=*(const float4*)&xw[(size_t)node*DD+li*4];
    a0+=v.x*wd; a1+=v.y*wd; a2+=v.z*wd; a3+=v.w*wd;
  }
  a0+=__shfl_xor(a0,32,64); a1+=__shfl_xor(a1,32,64);
  a2+=__shfl_xor(a2,32,64); a3+=__shfl_xor(a3,32,64);
  if(g==0){
    float wn=inv[node];
    float4 bv=*(const float4*)&bias[li*4];
    float4 o;
    o.x=a0*wn+bv.x; o.y=a1*wn+bv.y; o.z=a2*wn+bv.z; o.w=a3*wn+bv.w;
    *(float4*)&outp[(size_t)node*DD+li*4]=o;
  }
}

// ---------------- bf16 GCN aggregation: 4 edges per dwordx4 --------------
template<int MODE>
__global__ __launch_bounds__(256) void k_agg_b16(const uint32* __restrict__ xwb,
    const int* __restrict__ row_start, const int* __restrict__ csr,
    const float* __restrict__ inv, const float* __restrict__ bias,
    float* __restrict__ outp, const float* __restrict__ score,
    const unsigned char* __restrict__ sel, const float* __restrict__ addbuf,
    const int* __restrict__ list){
  int idx4=blockIdx.x*4+(threadIdx.x>>6);
  int node;
  if(MODE==1){ if(idx4>=KSEL) return; node=list[idx4]; }
  else { node=idx4; if(node>=NN) return; }
  int lane=threadIdx.x&63;
  int g=lane>>4, li=lane&15;
  int rs=row_start[node], re=row_start[node+1];
  float a[8];
  #pragma unroll
  for(int c=0;c<8;c++) a[c]=0.f;
  int j=rs;
  for(; j+7<re; j+=8){
    int sA=csr[j+g], sB=csr[j+4+g];
    if(MODE!=2 || sel[sA]){
      float w=inv[sA];
      uint4 u=*(const uint4*)(xwb+(size_t)sA*64+li*4);
      addbf2(a[0],a[1],u.x,w); addbf2(a[2],a[3],u.y,w);
      addbf2(a[4],a[5],u.z,w); addbf2(a[6],a[7],u.w,w);
    }
    if(MODE!=2 || sel[sB]){
      float w=inv[sB];
      uint4 u=*(const uint4*)(xwb+(size_t)sB*64+li*4);
      addbf2(a[0],a[1],u.x,w); addbf2(a[2],a[3],u.y,w);
      addbf2(a[4],a[5],u.z,w); addbf2(a[6],a[7],u.w,w);
    }
  }
  for(; j+3<re; j+=4){
    int s=csr[j+g];
    if(MODE!=2 || sel[s]){
      float w=inv[s];
      uint4 u=*(const uint4*)(xwb+(size_t)s*64+li*4);
      addbf2(a[0],a[1],u.x,w); addbf2(a[2],a[3],u.y,w);
      addbf2(a[4],a[5],u.z,w); addbf2(a[6],a[7],u.w,w);
    }
  }
  int rem=re-j;
  if(g<rem){
    int s=csr[j+g];
    if(MODE!=2 || sel[s]){
      float w=inv[s];
      uint4 u=*(const uint4*)(xwb+(size_t)s*64+li*4);
      addbf2(a[0],a[1],u.x,w); addbf2(a[2],a[3],u.y,w);
      addbf2(a[4],a[5],u.z,w); addbf2(a[6],a[7],u.w,w);
    }
  }
  if(g==0 && (MODE!=2 || sel[node])){
    float wd=inv[node];
    uint4 u=*(const uint4*)(xwb+(size_t)node*64+li*4);
    addbf2(a[0],a[1],u.x,wd); addbf2(a[2],a[3],u.y,wd);
    addbf2(a[4],a[5],u.z,wd); addbf2(a[6],a[7],u.w,wd);
  }
  #pragma unroll
  for(int c=0;c<8;c++){
    a[c]+=__shfl_xor(a[c],16,64);
    a[c]+=__shfl_xor(a[c],32,64);
  }
  if(g<2){
    float wn=inv[node];
    int cb=li*8+g*4;
    float4 bv=*(const float4*)&bias[cb];
    float r0=a[g*4+0]*wn+bv.x, r1=a[g*4+1]*wn+bv.y;
    float r2=a[g*4+2]*wn+bv.z, r3=a[g*4+3]*wn+bv.w;
    if(MODE==1){
      float sc=score[node];
      r0*=sc; r1*=sc; r2*=sc; r3*=sc;
    } else {
      float4 ad=*(const float4*)&addbuf[(size_t)node*DD+cb];
      r0+=ad.x; r1+=ad.y; r2+=ad.z; r3+=ad.w;
    }
    float4 o; o.x=r0; o.y=r1; o.z=r2; o.w=r3;
    *(float4*)&outp[(size_t)node*DD+cb]=o;
  }
}

// ============================================================================
extern "C" void kernel_launch(void* const* d_in, const int* in_sizes, int n_in,
                              void* d_out, int out_size, void* d_ws, size_t ws_size,
                              hipStream_t stream){
  const float* feat   =(const float*)d_in[0];
  const int*   ei     =(const int*)  d_in[2];
  const int*   src    = ei;
  const int*   dst    = ei + NE;
  const float* Wd     =(const float*)d_in[3];
  const float* bd     =(const float*)d_in[4];
  const float* prelu_a=(const float*)d_in[5];
  const float* Wbil   =(const float*)d_in[6];
  const float* bbil   =(const float*)d_in[7];
  const float* Wg1    =(const float*)d_in[8];
  const float* bg1    =(const float*)d_in[9];
  const float* Wg2    =(const float*)d_in[10];
  const float* bg2    =(const float*)d_in[11];
  const float* Wg3    =(const float*)d_in[12];
  const float* bg3    =(const float*)d_in[13];
  float* out=(float*)d_out;

  char* p=(char*)d_ws;
  auto alloc=[&](size_t bytes)->void*{ void* r=(void*)p; p+=((bytes+255)/256)*256; return r; };
  float* h_pos   =(float*)alloc((size_t)NN*DD*4);
  float* embed   =(float*)alloc((size_t)NN*DD*4);
  float* xw      =(float*)alloc((size_t)NN*DD*4);   // fp32 xw1 (K2..K5) / bf16 xw2,xw3 (K7..)
  float* score   =(float*)alloc((size_t)NN*4);
  float* inv_sq  =(float*)alloc((size_t)NN*4);
  float* WbT     =(float*)alloc((size_t)DD*DD*4);
  ushort16* Wt2b =(ushort16*)alloc((size_t)DD*DD*2);
  ushort16* Wt3b =(ushort16*)alloc((size_t)DD*DD*2);
  int*   row_st  =(int*)  alloc((size_t)(NN+1)*4);
  int*   csr_src =(int*)  alloc((size_t)NE*4);
  int*   ctrl    =(int*)  alloc(256);               // 64 ints: state + done counters
  int*   hist0   =(int*)  alloc(4096*4);
  int*   hist1   =(int*)  alloc(4096*4);
  int*   hist2   =(int*)  alloc(256*4);
  int*   tie_list=(int*)  alloc(4096*4);
  int*   list    =(int*)  alloc((size_t)KSEL*4);
  unsigned char* sel=(unsigned char*)alloc(NN);
  int*   boff    =(int*)  alloc((size_t)(NBK+1)*4);
  int*   blkcnt  =(int*)  alloc((size_t)BC*NBK*4);
  int*   blkbase =(int*)  alloc((size_t)BC*NBK*4);
  // pairs aliases EMBED (not xw!): pairs lives K3..K4; embed first written at K5
  // (full overwrite by agg_f32). R14 bug: pairs aliased xw, clobbering live xw1.
  uint32* pairs  =(uint32*)embed;
  ushort16* xwb  =(ushort16*)xw;
  float* fine = out;

  const int NB=(NN+255)/256;
  const int ABL=(KSEL+3)/4;

  // K1: GEMM1 | bcount | prep
  k_pack1<<<GB+BC+64,256,0,stream>>>(feat, Wd, bd, h_pos, prelu_a,
      dst, blkcnt, Wbil, WbT, Wg2, Wt2b, Wg3, Wt3b, ctrl);
  // K2: GEMM2 | bscan
  k_pack2<<<GB+1,256,0,stream>>>(h_pos, Wg1, xw, blkcnt, boff, blkbase, row_st);
  // K3/K4: scatter + finalize (pairs in embed region, dead after K4)
  k_bscatter<<<BC,256,0,stream>>>(src, dst, blkbase, pairs);
  k_bfinal  <<<BC,256,0,stream>>>(pairs, boff, row_st, inv_sq, csr_src);
  // K5: embed = gcn1 aggregation (fully overwrites embed/pairs region)
  k_agg_f32<<<AB,256,0,stream>>>(xw, row_st, csr_src, inv_sq, bg1, embed);
  // K6: score
  k_gemm_score<<<GB,256,0,stream>>>(embed, WbT, h_pos, bbil, score);
  // K7: mfma0 (embed@Wg2) | hist0
  k_pack3<<<GB+HB,256,0,stream>>>(embed, Wt2b, xwb, score, hist0, ctrl);
  // K8/K9: hist passes 1,2
  k_hist<4096,1><<<HB,256,0,stream>>>(score, hist1, ctrl);
  k_hist<256,2><<<HB,256,0,stream>>>(score, hist2, ctrl);
  // K10: mark + list + ties
  k_sel<<<NB,256,0,stream>>>(score, ctrl, tie_list, sel, list);
  // K11: fine[list] = (gcn2+bg2)*score
  k_agg_b16<1><<<ABL,256,0,stream>>>((const uint32*)xwb, row_st, csr_src, inv_sq, bg2, fine, score, sel, nullptr, list);
  // K12: xw3 = bf16(fine@Wg3) (selected rows)
  k_gemm_mfma1<<<GBL,256,0,stream>>>(fine, Wt3b, xwb, list);
  // K13: out = gcn3(fine) + embed
  k_agg_b16<2><<<AB,256,0,stream>>>((const uint32*)xwb, row_st, csr_src, inv_sq, bg3, out, nullptr, sel, embed, nullptr);
}

// Round 16
// 330.842 us; speedup vs baseline: 1.2913x; 1.2913x over previous
//
#include <hip/hip_runtime.h>
#include <hip/hip_bf16.h>

#define NN 50000
#define NE 800000
#define DD 128
#define KSEL 25000
#define NBK 391                 // buckets of 128 nodes
#define BB  98                  // build blocks (8192 edges each, 256 thr x 32 it)
#define AB 12500                // agg node-blocks (4 nodes/block)
#define GB 782                  // gemm blocks (64 rows)
#define GBL 391                 // compacted gemm blocks
#define HB 64                   // hist blocks

typedef unsigned int uint32;
typedef unsigned short ushort16;
typedef __attribute__((ext_vector_type(8))) short bf16x8;
typedef __attribute__((ext_vector_type(4))) float f32x4;

__device__ __forceinline__ float sigmoidf(float x){ return 1.f/(1.f+__expf(-x)); }

__device__ __forceinline__ unsigned short f2b(float f){
  union{float f; unsigned u;} v; v.f=f;
  unsigned r=(v.u + 0x7fffu + ((v.u>>16)&1u))>>16;
  return (unsigned short)r;
}

__device__ __forceinline__ void addbf2(float&lo,float&hi,uint32 u,float w){
  lo+=__uint_as_float(u<<16)*w;
  hi+=__uint_as_float(u&0xffff0000u)*w;
}

__device__ __forceinline__ int aload(const int* p){
  return __hip_atomic_load(p,__ATOMIC_RELAXED,__HIP_MEMORY_SCOPE_AGENT);
}

// ---------- fp32 GEMM body: 64x128 tile, 8 rows x 4 cols per thread ----------
template<int IN_SIG,int ACT>
__device__ __forceinline__ void gemm64_body(float (*Al)[132], int tid, int row0,
    const float* __restrict__ A, const float* __restrict__ W,
    const float* __restrict__ bias, float* __restrict__ outf,
    const float* __restrict__ aparam){
  {
    const float4* A4=(const float4*)(A+(size_t)row0*DD);
    #pragma unroll
    for(int i=0;i<8;i++){
      int idx=i*256+tid;
      int r=idx>>5, c=(idx&31)*4;
      float4 v=make_float4(0.f,0.f,0.f,0.f);
      if(row0+r<NN) v=A4[idx];
      if(IN_SIG){ v.x=sigmoidf(v.x); v.y=sigmoidf(v.y); v.z=sigmoidf(v.z); v.w=sigmoidf(v.w); }
      *(float4*)&Al[r][c]=v;
    }
  }
  __syncthreads();
  int tx=tid&31, ty=tid>>5;
  float acc[8][4];
  #pragma unroll
  for(int i=0;i<8;i++)
    #pragma unroll
    for(int c=0;c<4;c++) acc[i][c]=0.f;
  for(int k=0;k<DD;k+=4){
    float4 wv0=*(const float4*)&W[(size_t)(k+0)*DD+tx*4];
    float4 wv1=*(const float4*)&W[(size_t)(k+1)*DD+tx*4];
    float4 wv2=*(const float4*)&W[(size_t)(k+2)*DD+tx*4];
    float4 wv3=*(const float4*)&W[(size_t)(k+3)*DD+tx*4];
    #pragma unroll
    for(int i=0;i<8;i++){
      float4 a=*(const float4*)&Al[ty+8*i][k];
      acc[i][0]+=a.x*wv0.x+a.y*wv1.x+a.z*wv2.x+a.w*wv3.x;
      acc[i][1]+=a.x*wv0.y+a.y*wv1.y+a.z*wv2.y+a.w*wv3.y;
      acc[i][2]+=a.x*wv0.z+a.y*wv1.z+a.z*wv2.z+a.w*wv3.z;
      acc[i][3]+=a.x*wv0.w+a.y*wv1.w+a.z*wv2.w+a.w*wv3.w;
    }
  }
  float4 bv=make_float4(0.f,0.f,0.f,0.f);
  if(bias) bv=*(const float4*)&bias[tx*4];
  float ap=ACT?aparam[0]:0.f;
  #pragma unroll
  for(int i=0;i<8;i++){
    int r=row0+ty+8*i;
    if(r<NN){
      float4 o;
      o.x=acc[i][0]+bv.x; o.y=acc[i][1]+bv.y; o.z=acc[i][2]+bv.z; o.w=acc[i][3]+bv.w;
      if(ACT){
        o.x=o.x>=0.f?o.x:ap*o.x; o.y=o.y>=0.f?o.y:ap*o.y;
        o.z=o.z>=0.f?o.z:ap*o.z; o.w=o.w>=0.f?o.w:ap*o.w;
      }
      *(float4*)&outf[(size_t)r*DD+tx*4]=o;
    }
  }
}

// ---------- bf16 MFMA body ----------
template<int ROWLIST>
__device__ __forceinline__ void mfma_body(unsigned short (*Asl)[136],
    unsigned short (*Wsl)[136], int tid, int row0,
    const float* __restrict__ A, const ushort16* __restrict__ Wtb,
    ushort16* __restrict__ outb, const int* __restrict__ rlist){
  {
    const uint4* Wg=(const uint4*)Wtb;
    #pragma unroll
    for(int i=0;i<8;i++){
      int idx=i*256+tid;
      int n=idx>>4, k8=(idx&15)*8;
      uint4 v=Wg[idx];
      *(uint4*)&Wsl[n][k8]=v;
    }
  }
  {
    #pragma unroll
    for(int i=0;i<8;i++){
      int idx=i*256+tid;
      int r=idx>>5, c=(idx&31)*4;
      int gr; bool ok;
      if(ROWLIST){ int ri=row0+r; ok=(ri<KSEL); gr=ok?rlist[ri]:0; }
      else { gr=row0+r; ok=(gr<NN); }
      float4 v=make_float4(0.f,0.f,0.f,0.f);
      if(ok) v=*(const float4*)&A[(size_t)gr*DD+c];
      ushort4 pk;
      pk.x=f2b(v.x); pk.y=f2b(v.y); pk.z=f2b(v.z); pk.w=f2b(v.w);
      *(ushort4*)&Asl[r][c]=pk;
    }
  }
  __syncthreads();
  int lane=tid&63, w=tid>>6;
  int lr=lane&15, lk=lane>>4;
  f32x4 acc[8];
  #pragma unroll
  for(int nf=0;nf<8;nf++){ acc[nf][0]=0.f; acc[nf][1]=0.f; acc[nf][2]=0.f; acc[nf][3]=0.f; }
  #pragma unroll
  for(int kk=0;kk<4;kk++){
    int k0=kk*32+lk*8;
    bf16x8 a=*(bf16x8*)&Asl[w*16+lr][k0];
    #pragma unroll
    for(int nf=0;nf<8;nf++){
      bf16x8 b=*(bf16x8*)&Wsl[nf*16+lr][k0];
      acc[nf]=__builtin_amdgcn_mfma_f32_16x16x32_bf16(a,b,acc[nf],0,0,0);
    }
  }
  int orow[4]; bool ok[4];
  #pragma unroll
  for(int i=0;i<4;i++){
    int ri=row0+w*16+lk*4+i;
    if(ROWLIST){ ok[i]=(ri<KSEL); orow[i]=ok[i]?rlist[ri]:0; }
    else { orow[i]=ri; ok[i]=(ri<NN); }
  }
  #pragma unroll
  for(int nf=0;nf<8;nf++){
    int col=nf*16+lr;
    #pragma unroll
    for(int i=0;i<4;i++){
      if(ok[i]) outb[(size_t)orow[i]*DD+col]=f2b(acc[nf][i]);
    }
  }
}

// ====== K1: GEMM1 (feat@Wd,prelu) | bcount (98 superblocks) | prep ======
__global__ __launch_bounds__(256) void k_pack1(
    const float* __restrict__ feat, const float* __restrict__ Wd,
    const float* __restrict__ bd, float* __restrict__ h_pos,
    const float* __restrict__ aparam,
    const int* __restrict__ dst, int* __restrict__ blkcnt,
    const float* __restrict__ Wbil, float* __restrict__ WbT,
    const float* __restrict__ Wg2, ushort16* __restrict__ Wt2b,
    const float* __restrict__ Wg3, ushort16* __restrict__ Wt3b,
    int* __restrict__ zspan){
  __shared__ float Al[64][132];
  int bid=blockIdx.x, tid=threadIdx.x;
  if(bid<GB){
    gemm64_body<0,1>(Al, tid, bid*64, feat, Wd, bd, h_pos, aparam);
    return;
  }
  if(bid<GB+BB){
    int b=bid-GB;
    int* h=(int*)Al;
    for(int i=tid;i<NBK;i+=256) h[i]=0;
    __syncthreads();
    int e0=b*8192;
    #pragma unroll 8
    for(int t=0;t<32;t++){
      int e=e0+t*256+tid;
      if(e<NE) atomicAdd(&h[dst[e]>>7],1);
    }
    __syncthreads();
    for(int i=tid;i<NBK;i+=256) blkcnt[b*NBK+i]=h[i];
    return;
  }
  // prep
  int i=(bid-GB-BB)*256+tid;             // 0..16383
  if(i<DD*DD){
    int n=i>>7, k=i&127;
    WbT[i]=Wbil[k*DD+n];
    Wt2b[i]=f2b(Wg2[(size_t)k*DD+n]);
    Wt3b[i]=f2b(Wg3[(size_t)k*DD+n]);
  }
  if(i<8512) zspan[i]=0;                 // ctrl(64) + hist0(4096) + hist1(4096) + hist2(256)
}

// ====== K2: GEMM2 (h_pos@Wg1) | bscan (98-long serial loops) ======
__global__ __launch_bounds__(256) void k_pack2(
    const float* __restrict__ h_pos, const float* __restrict__ Wg1,
    float* __restrict__ xw,
    const int* __restrict__ blkcnt, int* __restrict__ boff,
    int* __restrict__ blkbase, int* __restrict__ row_start){
  __shared__ float Al[64][132];
  int bid=blockIdx.x, tid=threadIdx.x;
  if(bid<GB){
    gemm64_body<0,0>(Al, tid, bid*64, h_pos, Wg1, nullptr, xw, nullptr);
    return;
  }
  // bscan: 256 threads, buckets tid and tid+256
  int* sd=(int*)Al;                      // 512 ints
  int b0=tid, b1=tid+256;
  int s0=0, s1=0;
  for(int b=0;b<BB;b++){
    s0+=blkcnt[b*NBK+b0];
    if(b1<NBK) s1+=blkcnt[b*NBK+b1];
  }
  sd[b0]=s0; sd[b1]=(b1<NBK)?s1:0;
  __syncthreads();
  for(int off=1;off<512;off<<=1){
    int a0=(b0>=off)?sd[b0-off]:0;
    int a1=(b1>=off)?sd[b1-off]:0;
    __syncthreads();
    sd[b0]+=a0; sd[b1]+=a1;
    __syncthreads();
  }
  int excl0=sd[b0]-s0;
  boff[b0]=excl0;
  int excl1=0;
  if(b1<NBK){ excl1=sd[b1]-s1; boff[b1]=excl1; }
  if(tid==0){ boff[NBK]=NE; row_start[NN]=NE; }
  {
    int run=excl0;
    for(int b=0;b<BB;b++){
      int c=blkcnt[b*NBK+b0];
      blkbase[b*NBK+b0]=run;
      run+=c;
    }
  }
  if(b1<NBK){
    int run=excl1;
    for(int b=0;b<BB;b++){
      int c=blkcnt[b*NBK+b1];
      blkbase[b*NBK+b1]=run;
      run+=c;
    }
  }
}

// ---------------- bscatter (98 blocks, 256 thr, 8192 edges/block) ------------
__global__ __launch_bounds__(256) void k_bscatter(const int* __restrict__ src,
    const int* __restrict__ dst, const int* __restrict__ blkbase, uint32* __restrict__ pairs){
  __shared__ int cur[NBK];
  int tid=threadIdx.x, b=blockIdx.x;
  for(int i=tid;i<NBK;i+=256) cur[i]=blkbase[b*NBK+i];
  __syncthreads();
  int e0=b*8192;
  #pragma unroll 8
  for(int t=0;t<32;t++){
    int e=e0+t*256+tid;
    if(e<NE){
      int d=dst[e];
      int p=atomicAdd(&cur[d>>7],1);
      pairs[p]=(unsigned)src[e] | ((unsigned)(d&127)<<17);
    }
  }
}

__global__ __launch_bounds__(256) void k_bfinal(const uint32* __restrict__ pairs,
    const int* __restrict__ boff, int* __restrict__ row_start,
    float* __restrict__ inv_sq, int* __restrict__ csr_src){
  __shared__ int degl[128];
  __shared__ int cur[128];
  __shared__ int ssum[2];
  int b=blockIdx.x, tid=threadIdx.x;
  int lo=boff[b], hi=boff[b+1];
  if(tid<128) degl[tid]=0;
  __syncthreads();
  for(int e=lo+tid;e<hi;e+=256) atomicAdd(&degl[pairs[e]>>17],1);
  __syncthreads();
  int v=0,x=0;
  if(tid<128){
    v=degl[tid]; x=v;
    #pragma unroll
    for(int off=1;off<64;off<<=1){
      int y=__shfl_up(x,off,64);
      if((tid&63)>=off) x+=y;
    }
    if((tid&63)==63) ssum[tid>>6]=x;
  }
  __syncthreads();
  if(tid<128){
    int incl=x+((tid>=64)?ssum[0]:0);
    int node=b*128+tid;
    int excl=lo+incl-v;
    if(node<NN){
      row_start[node]=excl;
      cur[tid]=excl;
      inv_sq[node]=1.f/sqrtf((float)(v+1));
    }
  }
  __syncthreads();
  for(int e=lo+tid;e<hi;e+=256){
    uint32 u=pairs[e];
    int p=atomicAdd(&cur[u>>17],1);
    csr_src[p]=(int)(u&0x1FFFFu);
  }
}

// ---------------- score GEMM: sigmoid(embed)@WbT, fused bilinear score ------
__global__ __launch_bounds__(256) void k_gemm_score(const float* __restrict__ A,
    const float* __restrict__ W, const float* __restrict__ hp,
    const float* __restrict__ bbil, float* __restrict__ score){
  __shared__ float Al[64][132];
  int tid=threadIdx.x;
  int row0=blockIdx.x*64;
  {
    const float4* A4=(const float4*)(A+(size_t)row0*DD);
    #pragma unroll
    for(int i=0;i<8;i++){
      int idx=i*256+tid;
      int r=idx>>5, c=(idx&31)*4;
      float4 v=make_float4(0.f,0.f,0.f,0.f);
      if(row0+r<NN) v=A4[idx];
      v.x=sigmoidf(v.x); v.y=sigmoidf(v.y); v.z=sigmoidf(v.z); v.w=sigmoidf(v.w);
      *(float4*)&Al[r][c]=v;
    }
  }
  __syncthreads();
  int tx=tid&31, ty=tid>>5;
  float acc[8][4];
  #pragma unroll
  for(int i=0;i<8;i++)
    #pragma unroll
    for(int c=0;c<4;c++) acc[i][c]=0.f;
  for(int k=0;k<DD;k+=4){
    float4 wv0=*(const float4*)&W[(size_t)(k+0)*DD+tx*4];
    float4 wv1=*(const float4*)&W[(size_t)(k+1)*DD+tx*4];
    float4 wv2=*(const float4*)&W[(size_t)(k+2)*DD+tx*4];
    float4 wv3=*(const float4*)&W[(size_t)(k+3)*DD+tx*4];
    #pragma unroll
    for(int i=0;i<8;i++){
      float4 a=*(const float4*)&Al[ty+8*i][k];
      acc[i][0]+=a.x*wv0.x+a.y*wv1.x+a.z*wv2.x+a.w*wv3.x;
      acc[i][1]+=a.x*wv0.y+a.y*wv1.y+a.z*wv2.y+a.w*wv3.y;
      acc[i][2]+=a.x*wv0.z+a.y*wv1.z+a.z*wv2.z+a.w*wv3.z;
      acc[i][3]+=a.x*wv0.w+a.y*wv1.w+a.z*wv2.w+a.w*wv3.w;
    }
  }
  float bb=bbil[0];
  #pragma unroll
  for(int i=0;i<8;i++){
    int r=row0+ty+8*i;
    float p=0.f;
    if(r<NN){
      float4 h=*(const float4*)&hp[(size_t)r*DD+tx*4];
      p=acc[i][0]*h.x+acc[i][1]*h.y+acc[i][2]*h.z+acc[i][3]*h.w;
    }
    p+=__shfl_xor(p,16,64); p+=__shfl_xor(p,8,64);
    p+=__shfl_xor(p,4,64);  p+=__shfl_xor(p,2,64); p+=__shfl_xor(p,1,64);
    if(tx==0 && r<NN) score[r]=sigmoidf(p+bb);
  }
}

// ====== K7: mfma0 (embed@Wg2 -> xwb) | hist0 (findb fused in last block) ======
__global__ __launch_bounds__(256) void k_pack3(const float* __restrict__ embed,
    const ushort16* __restrict__ Wt2b, ushort16* __restrict__ outb,
    const float* __restrict__ score, int* __restrict__ ghist, int* __restrict__ ctrl){
  __shared__ __align__(16) unsigned short Asl[64][136];
  __shared__ __align__(16) unsigned short Wsl[128][136];
  __shared__ int lastf;
  int bid=blockIdx.x, tid=threadIdx.x;
  if(bid<GB){
    mfma_body<0>(Asl, Wsl, tid, bid*64, embed, Wt2b, outb, nullptr);
    return;
  }
  int hb=bid-GB;                         // 0..HB-1
  int* lh=(int*)Asl;                     // 4096 ints = 16 KB
  int* gs=(int*)Wsl;
  for(int i=tid;i<4096;i+=256) lh[i]=0;
  __syncthreads();
  for(int i=hb*256+tid;i<NN;i+=HB*256)
    atomicAdd(&lh[__float_as_uint(score[i])>>20],1);
  __syncthreads();
  for(int i=tid;i<4096;i+=256){ int v=lh[i]; if(v) atomicAdd(&ghist[i],v); }
  __syncthreads();
  if(tid==0){
    __threadfence();
    int v=atomicAdd(&ctrl[8],1);
    lastf=(v==HB-1);
  }
  __syncthreads();
  if(!lastf) return;
  int s=0;
  #pragma unroll
  for(int q=0;q<16;q++) s+=aload(&ghist[tid*16+q]);
  int x=s; gs[tid]=x; __syncthreads();
  for(int off=1;off<256;off<<=1){
    int y=(tid+off<256)?gs[tid+off]:0;
    __syncthreads(); x+=y; gs[tid]=x; __syncthreads();
  }
  int above=x-s, incl=x;
  if(above<KSEL && incl>=KSEL){
    int c=above, B=0;
    for(int b=15;b>=0;b--){
      int hb2=aload(&ghist[tid*16+b]);
      if(c+hb2>=KSEL){ B=tid*16+b; break; }
      c+=hb2;
    }
    ctrl[0]=B; ctrl[1]=c;
  }
}

// ====== hist passes 1,2 (findb fused into last block) ======
template<int NB,int PASS>
__global__ __launch_bounds__(256) void k_hist(const float* __restrict__ score,
    int* __restrict__ ghist, int* __restrict__ ctrl){
  __shared__ int lh[NB];
  __shared__ int gs[256];
  __shared__ int lastf;
  int tid=threadIdx.x;
  for(int i=tid;i<NB;i+=256) lh[i]=0;
  __syncthreads();
  int p0=0,p01=0;
  if(PASS==1) p0=ctrl[0];
  if(PASS==2) p01=ctrl[2];
  for(int i=blockIdx.x*256+tid; i<NN; i+=gridDim.x*256){
    unsigned b=__float_as_uint(score[i]);
    if(PASS==1){ if((int)(b>>20)==p0) atomicAdd(&lh[(b>>8)&0xFFF],1); }
    else { if((int)(b>>8)==p01) atomicAdd(&lh[b&0xFF],1); }
  }
  __syncthreads();
  for(int i=tid;i<NB;i+=256){ int v=lh[i]; if(v) atomicAdd(&ghist[i],v); }
  __syncthreads();
  if(tid==0){
    __threadfence();
    int v=atomicAdd(&ctrl[8+PASS],1);
    lastf=(v==(int)gridDim.x-1);
  }
  __syncthreads();
  if(!lastf) return;
  const int BPT=NB/256;
  int s=0;
  #pragma unroll
  for(int q=0;q<BPT;q++) s+=aload(&ghist[tid*BPT+q]);
  int x=s; gs[tid]=x; __syncthreads();
  for(int off=1;off<256;off<<=1){
    int y=(tid+off<256)?gs[tid+off]:0;
    __syncthreads(); x+=y; gs[tid]=x; __syncthreads();
  }
  int base=(PASS==1)?ctrl[1]:ctrl[3];
  int above=base+x-s, incl=base+x;
  if(above<KSEL && incl>=KSEL){
    int c=above, B=0;
    for(int b=BPT-1;b>=0;b--){
      int hb=aload(&ghist[tid*BPT+b]);
      if(c+hb>=KSEL){ B=tid*BPT+b; break; }
      c+=hb;
    }
    if(PASS==1){ ctrl[2]=(ctrl[0]<<12)|B; ctrl[3]=c; }
    else { ctrl[4]=(int)((((unsigned)ctrl[2])<<8)|(unsigned)B); ctrl[5]=KSEL-c; }
  }
}

// mark + compacted list; tie resolution fused into LAST block
__global__ __launch_bounds__(256) void k_sel(const float* __restrict__ score,
    int* __restrict__ ctrl, int* __restrict__ tie_list,
    unsigned char* __restrict__ sel, int* __restrict__ list){
  __shared__ int lastf;
  int tid=threadIdx.x;
  int i=blockIdx.x*256+tid;
  if(i<NN){
    unsigned b=__float_as_uint(score[i]);
    unsigned thr=(unsigned)ctrl[4];
    if(b>thr){
      sel[i]=1;
      int p=atomicAdd(&ctrl[7],1);
      list[p]=i;
    } else if(b==thr){
      sel[i]=0;
      int p=atomicAdd(&ctrl[6],1);
      if(p<4096) __hip_atomic_store(&tie_list[p],i,__ATOMIC_RELAXED,__HIP_MEMORY_SCOPE_AGENT);
    } else sel[i]=0;
  }
  __syncthreads();
  if(tid==0){
    __threadfence();
    int v=atomicAdd(&ctrl[11],1);
    lastf=(v==(int)gridDim.x-1);
  }
  __syncthreads();
  if(!lastf) return;
  int m=aload(&ctrl[6]); if(m>4096) m=4096;
  int needed=ctrl[5];
  for(int t=tid;t<m;t+=256){
    int idx=aload(&tie_list[t]);
    int rank=0;
    for(int j2=0;j2<m;j2++) rank+=(aload(&tie_list[j2])<idx)?1:0;
    if(rank<needed){
      sel[idx]=1;
      int p=atomicAdd(&ctrl[7],1);
      list[p]=idx;
    }
  }
}

// ============ standalone MFMA GEMM (ROWLIST) ============
__global__ __launch_bounds__(256) void k_gemm_mfma1(const float* __restrict__ A,
    const ushort16* __restrict__ Wtb, ushort16* __restrict__ outb,
    const int* __restrict__ rlist){
  __shared__ __align__(16) unsigned short Asl[64][136];
  __shared__ __align__(16) unsigned short Wsl[128][136];
  mfma_body<1>(Asl, Wsl, threadIdx.x, blockIdx.x*64, A, Wtb, outb, rlist);
}

// ---------------- fp32 GCN aggregation: 8-edge unroll ----------
__global__ __launch_bounds__(256) void k_agg_f32(const float* __restrict__ xw,
    const int* __restrict__ row_start, const int* __restrict__ csr,
    const float* __restrict__ inv, const float* __restrict__ bias,
    float* __restrict__ outp){
  int node=blockIdx.x*4+(threadIdx.x>>6);
  if(node>=NN) return;
  int lane=threadIdx.x&63;
  int g=lane>>5, li=lane&31;
  int rs=row_start[node], re=row_start[node+1];
  float a0=0.f,a1=0.f,a2=0.f,a3=0.f;
  int j=rs;
  for(; j+7<re; j+=8){
    int s0=csr[j+g], s1=csr[j+2+g], s2=csr[j+4+g], s3=csr[j+6+g];
    float w0=inv[s0], w1=inv[s1], w2=inv[s2], w3=inv[s3];
    float4 v0=*(const float4*)&xw[(size_t)s0*DD+li*4];
    float4 v1=*(const float4*)&xw[(size_t)s1*DD+li*4];
    float4 v2=*(const float4*)&xw[(size_t)s2*DD+li*4];
    float4 v3=*(const float4*)&xw[(size_t)s3*DD+li*4];
    a0+=v0.x*w0+v1.x*w1+v2.x*w2+v3.x*w3;
    a1+=v0.y*w0+v1.y*w1+v2.y*w2+v3.y*w3;
    a2+=v0.z*w0+v1.z*w1+v2.z*w2+v3.z*w3;
    a3+=v0.w*w0+v1.w*w1+v2.w*w2+v3.w*w3;
  }
  for(; j+1<re; j+=2){
    int s=csr[j+g];
    float w=inv[s];
    float4 v=*(const float4*)&xw[(size_t)s*DD+li*4];
    a0+=v.x*w; a1+=v.y*w; a2+=v.z*w; a3+=v.w*w;
  }
  if(j<re && g==0){
    int s=csr[j]; float w=inv[s];
    float4 v=*(const float4*)&xw[(size_t)s*DD+li*4];
    a0+=v.x*w; a1+=v.y*w; a2+=v.z*w; a3+=v.w*w;
  }
  if(g==0){
    float wd=inv[node];
    float4 v=*(const float4*)&xw[(size_t)node*DD+li*4];
    a0+=v.x*wd; a1+=v.y*wd; a2+=v.z*wd; a3+=v.w*wd;
  }
  a0+=__shfl_xor(a0,32,64); a1+=__shfl_xor(a1,32,64);
  a2+=__shfl_xor(a2,32,64); a3+=__shfl_xor(a3,32,64);
  if(g==0){
    float wn=inv[node];
    float4 bv=*(const float4*)&bias[li*4];
    float4 o;
    o.x=a0*wn+bv.x; o.y=a1*wn+bv.y; o.z=a2*wn+bv.z; o.w=a3*wn+bv.w;
    *(float4*)&outp[(size_t)node*DD+li*4]=o;
  }
}

// ---------------- bf16 GCN aggregation: 4 edges per dwordx4 --------------
template<int MODE>
__global__ __launch_bounds__(256) void k_agg_b16(const uint32* __restrict__ xwb,
    const int* __restrict__ row_start, const int* __restrict__ csr,
    const float* __restrict__ inv, const float* __restrict__ bias,
    float* __restrict__ outp, const float* __restrict__ score,
    const unsigned char* __restrict__ sel, const float* __restrict__ addbuf,
    const int* __restrict__ list){
  int idx4=blockIdx.x*4+(threadIdx.x>>6);
  int node;
  if(MODE==1){ if(idx4>=KSEL) return; node=list[idx4]; }
  else { node=idx4; if(node>=NN) return; }
  int lane=threadIdx.x&63;
  int g=lane>>4, li=lane&15;
  int rs=row_start[node], re=row_start[node+1];
  float a[8];
  #pragma unroll
  for(int c=0;c<8;c++) a[c]=0.f;
  int j=rs;
  for(; j+7<re; j+=8){
    int sA=csr[j+g], sB=csr[j+4+g];
    if(MODE!=2 || sel[sA]){
      float w=inv[sA];
      uint4 u=*(const uint4*)(xwb+(size_t)sA*64+li*4);
      addbf2(a[0],a[1],u.x,w); addbf2(a[2],a[3],u.y,w);
      addbf2(a[4],a[5],u.z,w); addbf2(a[6],a[7],u.w,w);
    }
    if(MODE!=2 || sel[sB]){
      float w=inv[sB];
      uint4 u=*(const uint4*)(xwb+(size_t)sB*64+li*4);
      addbf2(a[0],a[1],u.x,w); addbf2(a[2],a[3],u.y,w);
      addbf2(a[4],a[5],u.z,w); addbf2(a[6],a[7],u.w,w);
    }
  }
  for(; j+3<re; j+=4){
    int s=csr[j+g];
    if(MODE!=2 || sel[s]){
      float w=inv[s];
      uint4 u=*(const uint4*)(xwb+(size_t)s*64+li*4);
      addbf2(a[0],a[1],u.x,w); addbf2(a[2],a[3],u.y,w);
      addbf2(a[4],a[5],u.z,w); addbf2(a[6],a[7],u.w,w);
    }
  }
  int rem=re-j;
  if(g<rem){
    int s=csr[j+g];
    if(MODE!=2 || sel[s]){
      float w=inv[s];
      uint4 u=*(const uint4*)(xwb+(size_t)s*64+li*4);
      addbf2(a[0],a[1],u.x,w); addbf2(a[2],a[3],u.y,w);
      addbf2(a[4],a[5],u.z,w); addbf2(a[6],a[7],u.w,w);
    }
  }
  if(g==0 && (MODE!=2 || sel[node])){
    float wd=inv[node];
    uint4 u=*(const uint4*)(xwb+(size_t)node*64+li*4);
    addbf2(a[0],a[1],u.x,wd); addbf2(a[2],a[3],u.y,wd);
    addbf2(a[4],a[5],u.z,wd); addbf2(a[6],a[7],u.w,wd);
  }
  #pragma unroll
  for(int c=0;c<8;c++){
    a[c]+=__shfl_xor(a[c],16,64);
    a[c]+=__shfl_xor(a[c],32,64);
  }
  if(g<2){
    float wn=inv[node];
    int cb=li*8+g*4;
    float4 bv=*(const float4*)&bias[cb];
    float r0=a[g*4+0]*wn+bv.x, r1=a[g*4+1]*wn+bv.y;
    float r2=a[g*4+2]*wn+bv.z, r3=a[g*4+3]*wn+bv.w;
    if(MODE==1){
      float sc=score[node];
      r0*=sc; r1*=sc; r2*=sc; r3*=sc;
    } else {
      float4 ad=*(const float4*)&addbuf[(size_t)node*DD+cb];
      r0+=ad.x; r1+=ad.y; r2+=ad.z; r3+=ad.w;
    }
    float4 o; o.x=r0; o.y=r1; o.z=r2; o.w=r3;
    *(float4*)&outp[(size_t)node*DD+cb]=o;
  }
}

// ============================================================================
extern "C" void kernel_launch(void* const* d_in, const int* in_sizes, int n_in,
                              void* d_out, int out_size, void* d_ws, size_t ws_size,
                              hipStream_t stream){
  const float* feat   =(const float*)d_in[0];
  const int*   ei     =(const int*)  d_in[2];
  const int*   src    = ei;
  const int*   dst    = ei + NE;
  const float* Wd     =(const float*)d_in[3];
  const float* bd     =(const float*)d_in[4];
  const float* prelu_a=(const float*)d_in[5];
  const float* Wbil   =(const float*)d_in[6];
  const float* bbil   =(const float*)d_in[7];
  const float* Wg1    =(const float*)d_in[8];
  const float* bg1    =(const float*)d_in[9];
  const float* Wg2    =(const float*)d_in[10];
  const float* bg2    =(const float*)d_in[11];
  const float* Wg3    =(const float*)d_in[12];
  const float* bg3    =(const float*)d_in[13];
  float* out=(float*)d_out;

  char* p=(char*)d_ws;
  auto alloc=[&](size_t bytes)->void*{ void* r=(void*)p; p+=((bytes+255)/256)*256; return r; };
  float* h_pos   =(float*)alloc((size_t)NN*DD*4);
  float* embed   =(float*)alloc((size_t)NN*DD*4);
  float* xw      =(float*)alloc((size_t)NN*DD*4);   // fp32 xw1 (K2..K5) / bf16 xw2,xw3 (K7..)
  float* score   =(float*)alloc((size_t)NN*4);
  float* inv_sq  =(float*)alloc((size_t)NN*4);
  float* WbT     =(float*)alloc((size_t)DD*DD*4);
  ushort16* Wt2b =(ushort16*)alloc((size_t)DD*DD*2);
  ushort16* Wt3b =(ushort16*)alloc((size_t)DD*DD*2);
  int*   row_st  =(int*)  alloc((size_t)(NN+1)*4);
  int*   csr_src =(int*)  alloc((size_t)NE*4);
  int*   ctrl    =(int*)  alloc(256);               // 64 ints: state + done counters
  int*   hist0   =(int*)  alloc(4096*4);
  int*   hist1   =(int*)  alloc(4096*4);
  int*   hist2   =(int*)  alloc(256*4);
  int*   tie_list=(int*)  alloc(4096*4);
  int*   list    =(int*)  alloc((size_t)KSEL*4);
  unsigned char* sel=(unsigned char*)alloc(NN);
  int*   boff    =(int*)  alloc((size_t)(NBK+1)*4);
  int*   blkcnt  =(int*)  alloc((size_t)BB*NBK*4);
  int*   blkbase =(int*)  alloc((size_t)BB*NBK*4);
  // pairs aliases EMBED (not xw!): pairs lives K3..K4; embed first written at K5
  uint32* pairs  =(uint32*)embed;
  ushort16* xwb  =(ushort16*)xw;
  float* fine = out;

  const int NB=(NN+255)/256;
  const int ABL=(KSEL+3)/4;

  // K1: GEMM1 | bcount | prep
  k_pack1<<<GB+BB+64,256,0,stream>>>(feat, Wd, bd, h_pos, prelu_a,
      dst, blkcnt, Wbil, WbT, Wg2, Wt2b, Wg3, Wt3b, ctrl);
  // K2: GEMM2 | bscan
  k_pack2<<<GB+1,256,0,stream>>>(h_pos, Wg1, xw, blkcnt, boff, blkbase, row_st);
  // K3/K4: scatter + finalize (pairs in embed region, dead after K4)
  k_bscatter<<<BB,256,0,stream>>>(src, dst, blkbase, pairs);
  k_bfinal  <<<NBK,256,0,stream>>>(pairs, boff, row_st, inv_sq, csr_src);
  // K5: embed = gcn1 aggregation (fully overwrites embed/pairs region)
  k_agg_f32<<<AB,256,0,stream>>>(xw, row_st, csr_src, inv_sq, bg1, embed);
  // K6: score
  k_gemm_score<<<GB,256,0,stream>>>(embed, WbT, h_pos, bbil, score);
  // K7: mfma0 (embed@Wg2) | hist0
  k_pack3<<<GB+HB,256,0,stream>>>(embed, Wt2b, xwb, score, hist0, ctrl);
  // K8/K9: hist passes 1,2
  k_hist<4096,1><<<HB,256,0,stream>>>(score, hist1, ctrl);
  k_hist<256,2><<<HB,256,0,stream>>>(score, hist2, ctrl);
  // K10: mark + list + ties
  k_sel<<<NB,256,0,stream>>>(score, ctrl, tie_list, sel, list);
  // K11: fine[list] = (gcn2+bg2)*score
  k_agg_b16<1><<<ABL,256,0,stream>>>((const uint32*)xwb, row_st, csr_src, inv_sq, bg2, fine, score, sel, nullptr, list);
  // K12: xw3 = bf16(fine@Wg3) (selected rows)
  k_gemm_mfma1<<<GBL,256,0,stream>>>(fine, Wt3b, xwb, list);
  // K13: out = gcn3(fine) + embed
  k_agg_b16<2><<<AB,256,0,stream>>>((const uint32*)xwb, row_st, csr_src, inv_sq, bg3, out, nullptr, sel, embed, nullptr);
}